// Round 1
// 506.985 us; speedup vs baseline: 1.0522x; 1.0522x over previous
//
#include <hip/hip_runtime.h>
#include <hip/hip_fp16.h>
#include <math.h>

// Problem dims
#define LTOT 1024
#define BB   4
#define F_IN 32
#define DM   256
#define DI   512
#define DS   16
#define DTRN 16
#define NXP  48         // DTR + 2*DS
#define NLAY 4
#define NH   4
#define NC   16         // scan chunks
#define CLEN 64         // L / NC
#define ROWS (BB*LTOT)  // 4096

typedef _Float16 half8 __attribute__((ext_vector_type(8)));
typedef float f32x16 __attribute__((ext_vector_type(16)));
typedef unsigned short us8 __attribute__((ext_vector_type(8)));

__device__ __forceinline__ float siluf_(float x) { return x / (1.0f + expf(-x)); }
__device__ __forceinline__ float softplusf_(float x) {
    if (x > 20.f) return x;
    if (x < -20.f) return expf(x);
    return log1pf(expf(x));
}

// fp16 2-piece split: x ~= hi + lo with ~22-bit combined mantissa
__device__ __forceinline__ void split16(float x, unsigned short& hi, unsigned short& lo) {
    __half h = __float2half(x);
    hi = *(unsigned short*)&h;
    float r = x - __half2float(h);
    __half l = __float2half(r);
    lo = *(unsigned short*)&l;
}

// ---------------- split weights once (inproj_w all layers, outproj_w all layers) ----
__global__ __launch_bounds__(256) void k_splitw(const float* __restrict__ inw,
                                                const float* __restrict__ outw,
                                                unsigned short* __restrict__ iwh,
                                                unsigned short* __restrict__ iwl,
                                                unsigned short* __restrict__ owh,
                                                unsigned short* __restrict__ owl) {
    int q = blockIdx.x * 256 + threadIdx.x;   // quad index; grid covers exactly
    ushort4 h4, l4;
    if (q < 262144) {                          // 4*1024*256 / 4
        float4 v = ((const float4*)inw)[q];
        split16(v.x, h4.x, l4.x); split16(v.y, h4.y, l4.y);
        split16(v.z, h4.z, l4.z); split16(v.w, h4.w, l4.w);
        *(ushort4*)(iwh + (size_t)q * 4) = h4;
        *(ushort4*)(iwl + (size_t)q * 4) = l4;
    } else {
        int r = q - 262144;                    // 4*256*512 / 4 = 131072 quads
        float4 v = ((const float4*)outw)[r];
        split16(v.x, h4.x, l4.x); split16(v.y, h4.y, l4.y);
        split16(v.z, h4.z, l4.z); split16(v.w, h4.w, l4.w);
        *(ushort4*)(owh + (size_t)r * 4) = h4;
        *(ushort4*)(owl + (size_t)r * 4) = l4;
    }
}

// ---------------- proj: h = x @ proj_w.T + proj_b (+ fp16-split emit) ----------------
__global__ __launch_bounds__(256) void k_proj(const float* __restrict__ x,
                                              const float* __restrict__ pw,
                                              const float* __restrict__ pb,
                                              float* __restrict__ h,
                                              unsigned short* __restrict__ hh,
                                              unsigned short* __restrict__ hl) {
    __shared__ float wl[DM][33];
    __shared__ float xl[16][32];
    int t = threadIdx.x;
    int r0 = blockIdx.x * 16;
    for (int i = t; i < DM * 32 / 4; i += 256) {
        float4 v = ((const float4*)pw)[i];
        int c = i / 8, k = (i % 8) * 4;
        wl[c][k] = v.x; wl[c][k + 1] = v.y; wl[c][k + 2] = v.z; wl[c][k + 3] = v.w;
    }
    for (int i = t; i < 16 * 32 / 4; i += 256) {
        float4 v = ((const float4*)(x + (size_t)r0 * F_IN))[i];
        int r = i / 8, k = (i % 8) * 4;
        xl[r][k] = v.x; xl[r][k + 1] = v.y; xl[r][k + 2] = v.z; xl[r][k + 3] = v.w;
    }
    __syncthreads();
    int c = t;
    float bias = pb[c];
    float acc[16];
#pragma unroll
    for (int r = 0; r < 16; ++r) acc[r] = bias;
    for (int k = 0; k < 32; ++k) {
        float w = wl[c][k];
#pragma unroll
        for (int r = 0; r < 16; ++r) acc[r] = fmaf(xl[r][k], w, acc[r]);
    }
#pragma unroll
    for (int r = 0; r < 16; ++r) {
        size_t idx = (size_t)(r0 + r) * DM + c;
        h[idx] = acc[r];
        unsigned short vh, vl; split16(acc[r], vh, vl);
        hh[idx] = vh; hl[idx] = vl;
    }
}

// ---------------- gemm_xz (MFMA, pre-split fp16): xz = h @ inw^T ----------------
// 64x128 tile, grid 512 = 64 rowblk x 8 colblk (2 blocks/CU).
// 4 waves as 2 row-waves x 2 col-waves; per wave 32 rows x 64 cols.
__global__ __launch_bounds__(256) void k_gemm_xz(const unsigned short* __restrict__ Ahp,
                                                 const unsigned short* __restrict__ Alp,
                                                 const unsigned short* __restrict__ Bhp,
                                                 const unsigned short* __restrict__ Blp,
                                                 float* __restrict__ C) {
    __shared__ unsigned short Ah[64][40], Al[64][40], Bh[128][40], Bl[128][40];
    int t = threadIdx.x;
    int bx = blockIdx.x & 7;
    int by = blockIdx.x >> 3;
    int rowA = t >> 2, kA = (t & 3) * 8;   // 64 rows x 4 granules of 8 ushorts
    int rowB = t >> 1, kB = (t & 1) * 16;  // 128 rows x 2 granules of 16 ushorts
    const unsigned short* ApH = Ahp + (size_t)(by * 64 + rowA) * DM + kA;
    const unsigned short* ApL = Alp + (size_t)(by * 64 + rowA) * DM + kA;
    const unsigned short* BpH = Bhp + (size_t)(bx * 128 + rowB) * DM + kB;
    const unsigned short* BpL = Blp + (size_t)(bx * 128 + rowB) * DM + kB;
    us8 rah = *(const us8*)ApH, ral = *(const us8*)ApL;
    us8 rbh0 = *(const us8*)BpH, rbh1 = *(const us8*)(BpH + 8);
    us8 rbl0 = *(const us8*)BpL, rbl1 = *(const us8*)(BpL + 8);
    int lane = t & 63, wid = t >> 6;
    int fr = lane & 31, fg = lane >> 5;
    int wr = wid >> 1, wc = wid & 1;
    f32x16 acc[2] = {};
    for (int k0 = 0; k0 < DM; k0 += 32) {
        *(us8*)&Ah[rowA][kA] = rah;
        *(us8*)&Al[rowA][kA] = ral;
        *(us8*)&Bh[rowB][kB] = rbh0; *(us8*)&Bh[rowB][kB + 8] = rbh1;
        *(us8*)&Bl[rowB][kB] = rbl0; *(us8*)&Bl[rowB][kB + 8] = rbl1;
        __syncthreads();
        if (k0 + 32 < DM) {
            rah = *(const us8*)(ApH + k0 + 32); ral = *(const us8*)(ApL + k0 + 32);
            rbh0 = *(const us8*)(BpH + k0 + 32); rbh1 = *(const us8*)(BpH + k0 + 40);
            rbl0 = *(const us8*)(BpL + k0 + 32); rbl1 = *(const us8*)(BpL + k0 + 40);
        }
#pragma unroll
        for (int s = 0; s < 2; ++s) {
            int ko = s * 16 + fg * 8;
            half8 ah = *(const half8*)&Ah[wr * 32 + fr][ko];
            half8 al = *(const half8*)&Al[wr * 32 + fr][ko];
#pragma unroll
            for (int fc = 0; fc < 2; ++fc) {
                half8 bh = *(const half8*)&Bh[wc * 64 + fc * 32 + fr][ko];
                half8 bl = *(const half8*)&Bl[wc * 64 + fc * 32 + fr][ko];
                acc[fc] = __builtin_amdgcn_mfma_f32_32x32x16_f16(ah, bh, acc[fc], 0, 0, 0);
                acc[fc] = __builtin_amdgcn_mfma_f32_32x32x16_f16(ah, bl, acc[fc], 0, 0, 0);
                acc[fc] = __builtin_amdgcn_mfma_f32_32x32x16_f16(al, bh, acc[fc], 0, 0, 0);
            }
        }
        __syncthreads();
    }
    // C/D layout (32x32): col = lane&31, row = (reg&3) + 8*(reg>>2) + 4*(lane>>5)
    float* Cp = C + (size_t)(by * 64 + wr * 32) * 1024 + bx * 128 + wc * 64;
#pragma unroll
    for (int fc = 0; fc < 2; ++fc) {
#pragma unroll
        for (int reg = 0; reg < 16; ++reg) {
            int row = (reg & 3) + 8 * (reg >> 2) + 4 * fg;
            Cp[(size_t)row * 1024 + fc * 32 + fr] = acc[fc][reg];
        }
    }
}

// ---------------- causal conv (DC=4) + silu ----------------
__global__ __launch_bounds__(256) void k_conv(const float* __restrict__ xz,
                                              const float* __restrict__ cw,
                                              const float* __restrict__ cb,
                                              float* __restrict__ uc) {
    int gid = blockIdx.x * 256 + threadIdx.x;
    if (gid >= ROWS * (DI / 4)) return;
    int r = gid / (DI / 4);
    int d = (gid % (DI / 4)) * 4;
    int tt = r & (LTOT - 1);
    float4 acc = make_float4(cb[d], cb[d + 1], cb[d + 2], cb[d + 3]);
#pragma unroll
    for (int k = 0; k < 4; ++k) {
        int ts = tt - 3 + k;
        if (ts < 0) continue;
        float4 u = *(const float4*)(xz + (size_t)(r - 3 + k) * 1024 + d);
        acc.x = fmaf(u.x, cw[(d + 0) * 4 + k], acc.x);
        acc.y = fmaf(u.y, cw[(d + 1) * 4 + k], acc.y);
        acc.z = fmaf(u.z, cw[(d + 2) * 4 + k], acc.z);
        acc.w = fmaf(u.w, cw[(d + 3) * 4 + k], acc.w);
    }
    acc.x = siluf_(acc.x); acc.y = siluf_(acc.y); acc.z = siluf_(acc.z); acc.w = siluf_(acc.w);
    *(float4*)(uc + (size_t)r * DI + d) = acc;
}

// ---------------- dbc partial GEMM (split-K by 4) ----------------
__global__ __launch_bounds__(256) void k_dbcp(const float* __restrict__ uc,
                                              const float* __restrict__ xpw,
                                              float* __restrict__ xz) {
    __shared__ float us[32][132];
    __shared__ float wsd[48][132];
    int t = threadIdx.x;
    int kp = blockIdx.x & 3;
    int r0 = (blockIdx.x >> 2) * 32;
    int k0 = kp * 128;
    float4* us4 = (float4*)us;
    float4* ws4 = (float4*)wsd;
#pragma unroll
    for (int j = 0; j < 4; ++j) {
        int i = t + j * 256;
        int r = i >> 5, kq = i & 31;
        us4[r * 33 + kq] = *(const float4*)(uc + (size_t)(r0 + r) * DI + k0 + kq * 4);
    }
#pragma unroll
    for (int j = 0; j < 6; ++j) {
        int i = t + j * 256;
        int r = i >> 5, kq = i & 31;
        ws4[r * 33 + kq] = *(const float4*)(xpw + (size_t)r * DI + k0 + kq * 4);
    }
    __syncthreads();
    int tx = t & 15, ty = t >> 4;
    const float4* ua = us4 + (ty * 2) * 33;
    const float4* ub = ua + 33;
    const float4* w0p = ws4 + (tx * 3) * 33;
    const float4* w1p = w0p + 33;
    const float4* w2p = w0p + 66;
    float acc[2][3] = {};
#pragma unroll 4
    for (int kq = 0; kq < 32; ++kq) {
        float4 u0 = ua[kq], u1 = ub[kq];
        float4 w0 = w0p[kq], w1 = w1p[kq], w2 = w2p[kq];
        acc[0][0] = fmaf(u0.x, w0.x, acc[0][0]); acc[0][0] = fmaf(u0.y, w0.y, acc[0][0]);
        acc[0][0] = fmaf(u0.z, w0.z, acc[0][0]); acc[0][0] = fmaf(u0.w, w0.w, acc[0][0]);
        acc[0][1] = fmaf(u0.x, w1.x, acc[0][1]); acc[0][1] = fmaf(u0.y, w1.y, acc[0][1]);
        acc[0][1] = fmaf(u0.z, w1.z, acc[0][1]); acc[0][1] = fmaf(u0.w, w1.w, acc[0][1]);
        acc[0][2] = fmaf(u0.x, w2.x, acc[0][2]); acc[0][2] = fmaf(u0.y, w2.y, acc[0][2]);
        acc[0][2] = fmaf(u0.z, w2.z, acc[0][2]); acc[0][2] = fmaf(u0.w, w2.w, acc[0][2]);
        acc[1][0] = fmaf(u1.x, w0.x, acc[1][0]); acc[1][0] = fmaf(u1.y, w0.y, acc[1][0]);
        acc[1][0] = fmaf(u1.z, w0.z, acc[1][0]); acc[1][0] = fmaf(u1.w, w0.w, acc[1][0]);
        acc[1][1] = fmaf(u1.x, w1.x, acc[1][1]); acc[1][1] = fmaf(u1.y, w1.y, acc[1][1]);
        acc[1][1] = fmaf(u1.z, w1.z, acc[1][1]); acc[1][1] = fmaf(u1.w, w1.w, acc[1][1]);
        acc[1][2] = fmaf(u1.x, w2.x, acc[1][2]); acc[1][2] = fmaf(u1.y, w2.y, acc[1][2]);
        acc[1][2] = fmaf(u1.z, w2.z, acc[1][2]); acc[1][2] = fmaf(u1.w, w2.w, acc[1][2]);
    }
    float* outp = xz + (size_t)(r0 + ty * 2) * 1024 + kp * 48 + tx * 3;
    outp[0] = acc[0][0]; outp[1] = acc[0][1]; outp[2] = acc[0][2];
    outp[1024] = acc[1][0]; outp[1025] = acc[1][1]; outp[1026] = acc[1][2];
}

// ---------------- dbc reduce + BC extract + delta ----------------
__global__ __launch_bounds__(256) void k_dbcr(const float* __restrict__ xzp,
                                              const float* __restrict__ dtw,
                                              const float* __restrict__ dtb,
                                              float* __restrict__ delta,
                                              float* __restrict__ BC) {
    __shared__ float dbl[16][NXP];
    int t = threadIdx.x;
    int r0 = blockIdx.x * 16;
    {
        int r = t >> 4, c3 = (t & 15) * 3;
        const float* pp = xzp + (size_t)(r0 + r) * 1024 + c3;
#pragma unroll
        for (int j = 0; j < 3; ++j) {
            float s = pp[j] + pp[48 + j] + pp[96 + j] + pp[144 + j];
            dbl[r][c3 + j] = s;
            int cj = c3 + j;
            if (cj >= 16) BC[(size_t)(r0 + r) * 32 + (cj - 16)] = s;
        }
    }
    __syncthreads();
    {
        int c0 = t * 2;
        float wd0[16], wd1[16];
        const float4* q0 = (const float4*)(dtw + (size_t)c0 * 16);
        const float4* q1 = (const float4*)(dtw + (size_t)(c0 + 1) * 16);
#pragma unroll
        for (int j = 0; j < 4; ++j) { *(float4*)&wd0[j * 4] = q0[j]; *(float4*)&wd1[j * 4] = q1[j]; }
        float bb0 = dtb[c0], bb1 = dtb[c0 + 1];
        for (int r = 0; r < 16; ++r) {
            float s0 = bb0, s1 = bb1;
#pragma unroll
            for (int k = 0; k < 16; ++k) {
                float dv = dbl[r][k];
                s0 = fmaf(dv, wd0[k], s0);
                s1 = fmaf(dv, wd1[k], s1);
            }
            *(float2*)(delta + (size_t)(r0 + r) * DI + c0) =
                make_float2(softplusf_(s0), softplusf_(s1));
        }
    }
}

// ---------------- scan pass A ----------------
__global__ __launch_bounds__(256) void k_scanA(const float* __restrict__ delta,
                                               const float* __restrict__ uc,
                                               const float* __restrict__ BC,
                                               const float* __restrict__ A_log,
                                               float* __restrict__ P,
                                               float* __restrict__ hL) {
    __shared__ float2 du2[CLEN][16];
    __shared__ float  Bl[CLEN][16];
    int bid = blockIdx.x;
    int c = bid & 15, dblk = (bid >> 4) & 31, b = bid >> 9;
    int d0 = dblk * 16, t0 = c * CLEN;
    int t = threadIdx.x;
    {
        int row = t >> 2, hf = (t & 3) * 4;
        size_t rbase = (size_t)(b * LTOT + t0 + row);
        float4 dv = *(const float4*)(delta + rbase * DI + d0 + hf);
        float4 uv = *(const float4*)(uc + rbase * DI + d0 + hf);
        float4* dst = (float4*)&du2[row][hf];
        dst[0] = make_float4(dv.x, uv.x, dv.y, uv.y);
        dst[1] = make_float4(dv.z, uv.z, dv.w, uv.w);
        *(float4*)&Bl[row][hf] = *(const float4*)(BC + rbase * 32 + hf);
    }
    __syncthreads();
    int n = t & 15, dn = t >> 4;
    float Ac = -expf(A_log[(size_t)(d0 + dn) * DS + n]);
    float h = 0.f, Pp = 1.f;
#pragma unroll 8
    for (int k = 0; k < CLEN; ++k) {
        float2 du = du2[k][dn];
        float Bv = Bl[k][n];
        float a = expf(du.x * Ac);
        Pp *= a;
        h = fmaf(a, h, du.x * du.y * Bv);
    }
    size_t idx = ((size_t)(b * NC + c)) * (DI * DS) + (size_t)d0 * DS + t;
    P[idx] = Pp;
    hL[idx] = h;
}

// ---------------- scan pass C (emits fp16-split y directly) ----------------
__global__ __launch_bounds__(256) void k_scanC(const float* __restrict__ delta,
                                               const float* __restrict__ uc,
                                               const float* __restrict__ BC,
                                               const float* __restrict__ A_log,
                                               const float* __restrict__ P,
                                               const float* __restrict__ hL,
                                               const float* __restrict__ Dp,
                                               const float* __restrict__ xz,
                                               unsigned short* __restrict__ yh,
                                               unsigned short* __restrict__ yl) {
    __shared__ float2 du2[CLEN][16];
    __shared__ float2 bc2[CLEN][16];
    __shared__ float  ytmp[16][16][20];
    int bid = blockIdx.x;
    int c = bid & 15, dblk = (bid >> 4) & 31, b = bid >> 9;
    int d0 = dblk * 16, t0 = c * CLEN;
    int t = threadIdx.x;
    {
        int row = t >> 2, hf = (t & 3) * 4;
        size_t rbase = (size_t)(b * LTOT + t0 + row);
        float4 dv = *(const float4*)(delta + rbase * DI + d0 + hf);
        float4 uv = *(const float4*)(uc + rbase * DI + d0 + hf);
        float4* dst = (float4*)&du2[row][hf];
        dst[0] = make_float4(dv.x, uv.x, dv.y, uv.y);
        dst[1] = make_float4(dv.z, uv.z, dv.w, uv.w);
        float4 bv = *(const float4*)(BC + rbase * 32 + hf);
        float4 cv = *(const float4*)(BC + rbase * 32 + 16 + hf);
        float4* bdst = (float4*)&bc2[row][hf];
        bdst[0] = make_float4(bv.x, cv.x, bv.y, cv.y);
        bdst[1] = make_float4(bv.z, cv.z, bv.w, cv.w);
    }
    __syncthreads();
    int n = t & 15, dn = t >> 4;
    float Ac = -expf(A_log[(size_t)(d0 + dn) * DS + n]);
    float Hin = 0.f;
    for (int cc = 0; cc < c; ++cc) {
        size_t idx = ((size_t)(b * NC + cc)) * (DI * DS) + (size_t)d0 * DS + t;
        Hin = fmaf(P[idx], Hin, hL[idx]);
    }
    float h = Hin;
    int rdn = t & 15, rk = t >> 4;
    float DpV = Dp[d0 + rdn];
    for (int s = 0; s < CLEN / 16; ++s) {
#pragma unroll
        for (int kk = 0; kk < 16; ++kk) {
            int k = s * 16 + kk;
            float2 du = du2[k][dn];
            float2 bc = bc2[k][n];
            float a = expf(du.x * Ac);
            h = fmaf(a, h, du.x * du.y * bc.x);
            ytmp[kk][dn][n] = h * bc.y;
        }
        __syncthreads();
        {
            const float* rowp = &ytmp[rk][rdn][0];
            float4 v0 = *(const float4*)(rowp + 0);
            float4 v1 = *(const float4*)(rowp + 4);
            float4 v2 = *(const float4*)(rowp + 8);
            float4 v3 = *(const float4*)(rowp + 12);
            float y = ((v0.x + v0.y) + (v0.z + v0.w)) + ((v1.x + v1.y) + (v1.z + v1.w))
                    + ((v2.x + v2.y) + (v2.z + v2.w)) + ((v3.x + v3.y) + (v3.z + v3.w));
            float uu = du2[s * 16 + rk][rdn].y;
            size_t rb2 = (size_t)(b * LTOT + t0 + s * 16 + rk);
            float z = xz[rb2 * 1024 + 512 + d0 + rdn];
            float val = fmaf(uu, DpV, y) * siluf_(z);
            unsigned short vh, vl; split16(val, vh, vl);
            size_t yi = rb2 * DI + d0 + rdn;
            yh[yi] = vh; yl[yi] = vl;
        }
        __syncthreads();
    }
}

// ---------------- gemm_out (MFMA, pre-split fp16, split-K4): blk = yz @ outw^T ----
// 64x128 tile, grid 512: bx = bid&1, by = (bid>>1)&63, kp = bid>>7 (K=128 slice).
__global__ __launch_bounds__(256) void k_gemm_out(const unsigned short* __restrict__ Ahp,
                                                  const unsigned short* __restrict__ Alp,
                                                  const unsigned short* __restrict__ Bhp,
                                                  const unsigned short* __restrict__ Blp,
                                                  float* __restrict__ p01,
                                                  float* __restrict__ p23) {
    __shared__ unsigned short Ah[64][40], Al[64][40], Bh[128][40], Bl[128][40];
    int t = threadIdx.x;
    int bx = blockIdx.x & 1;
    int by = (blockIdx.x >> 1) & 63;
    int kp = blockIdx.x >> 7;
    int rowA = t >> 2, kA = (t & 3) * 8;
    int rowB = t >> 1, kB = (t & 1) * 16;
    const unsigned short* ApH = Ahp + (size_t)(by * 64 + rowA) * DI + kp * 128 + kA;
    const unsigned short* ApL = Alp + (size_t)(by * 64 + rowA) * DI + kp * 128 + kA;
    const unsigned short* BpH = Bhp + (size_t)(bx * 128 + rowB) * DI + kp * 128 + kB;
    const unsigned short* BpL = Blp + (size_t)(bx * 128 + rowB) * DI + kp * 128 + kB;
    us8 rah = *(const us8*)ApH, ral = *(const us8*)ApL;
    us8 rbh0 = *(const us8*)BpH, rbh1 = *(const us8*)(BpH + 8);
    us8 rbl0 = *(const us8*)BpL, rbl1 = *(const us8*)(BpL + 8);
    int lane = t & 63, wid = t >> 6;
    int fr = lane & 31, fg = lane >> 5;
    int wr = wid >> 1, wc = wid & 1;
    f32x16 acc[2] = {};
    for (int k0 = 0; k0 < 128; k0 += 32) {
        *(us8*)&Ah[rowA][kA] = rah;
        *(us8*)&Al[rowA][kA] = ral;
        *(us8*)&Bh[rowB][kB] = rbh0; *(us8*)&Bh[rowB][kB + 8] = rbh1;
        *(us8*)&Bl[rowB][kB] = rbl0; *(us8*)&Bl[rowB][kB + 8] = rbl1;
        __syncthreads();
        if (k0 + 32 < 128) {
            rah = *(const us8*)(ApH + k0 + 32); ral = *(const us8*)(ApL + k0 + 32);
            rbh0 = *(const us8*)(BpH + k0 + 32); rbh1 = *(const us8*)(BpH + k0 + 40);
            rbl0 = *(const us8*)(BpL + k0 + 32); rbl1 = *(const us8*)(BpL + k0 + 40);
        }
#pragma unroll
        for (int s = 0; s < 2; ++s) {
            int ko = s * 16 + fg * 8;
            half8 ah = *(const half8*)&Ah[wr * 32 + fr][ko];
            half8 al = *(const half8*)&Al[wr * 32 + fr][ko];
#pragma unroll
            for (int fc = 0; fc < 2; ++fc) {
                half8 bh = *(const half8*)&Bh[wc * 64 + fc * 32 + fr][ko];
                half8 bl = *(const half8*)&Bl[wc * 64 + fc * 32 + fr][ko];
                acc[fc] = __builtin_amdgcn_mfma_f32_32x32x16_f16(ah, bh, acc[fc], 0, 0, 0);
                acc[fc] = __builtin_amdgcn_mfma_f32_32x32x16_f16(ah, bl, acc[fc], 0, 0, 0);
                acc[fc] = __builtin_amdgcn_mfma_f32_32x32x16_f16(al, bh, acc[fc], 0, 0, 0);
            }
        }
        __syncthreads();
    }
    float* pbase = (kp < 2 ? p01 : p23) + (size_t)(kp & 1) * (ROWS * DM);
    float* Cp = pbase + (size_t)(by * 64 + wr * 32) * DM + bx * 128 + wc * 64;
#pragma unroll
    for (int fc = 0; fc < 2; ++fc) {
#pragma unroll
        for (int reg = 0; reg < 16; ++reg) {
            int row = (reg & 3) + 8 * (reg >> 2) + 4 * fg;
            Cp[(size_t)row * DM + fc * 32 + fr] = acc[fc][reg];
        }
    }
}

// ---------------- layernorm + residual (sums 4 gemm_out partials, emits h16) --------
__global__ __launch_bounds__(256) void k_ln_res(const float* __restrict__ p01,
                                                const float* __restrict__ p23,
                                                const float* __restrict__ g,
                                                const float* __restrict__ bb,
                                                float* __restrict__ h,
                                                unsigned short* __restrict__ hh,
                                                unsigned short* __restrict__ hl) {
    __shared__ float scratch[4];
    int r = blockIdx.x, t = threadIdx.x;
    size_t idx = (size_t)r * DM + t;
    float v = p01[idx] + p01[idx + (size_t)ROWS * DM] + p23[idx] + p23[idx + (size_t)ROWS * DM];
    float s = v;
#pragma unroll
    for (int m = 32; m >= 1; m >>= 1) s += __shfl_xor(s, m, 64);
    if ((t & 63) == 0) scratch[t >> 6] = s;
    __syncthreads();
    float mu = (scratch[0] + scratch[1] + scratch[2] + scratch[3]) * (1.f / DM);
    __syncthreads();
    float d = v - mu;
    float s2 = d * d;
#pragma unroll
    for (int m = 32; m >= 1; m >>= 1) s2 += __shfl_xor(s2, m, 64);
    if ((t & 63) == 0) scratch[t >> 6] = s2;
    __syncthreads();
    float var = (scratch[0] + scratch[1] + scratch[2] + scratch[3]) * (1.f / DM);
    float rstd = 1.f / sqrtf(var + 1e-5f);
    float nv = h[idx] + d * rstd * g[t] + bb[t];
    h[idx] = nv;
    unsigned short vh, vl; split16(nv, vh, vl);
    hh[idx] = vh; hl[idx] = vl;
}

// ---------------- mean over L (partials, deterministic) ----------------
__global__ __launch_bounds__(256) void k_meanp(const float* __restrict__ h,
                                               float* __restrict__ part) {
    int bid = blockIdx.x;
    int b = bid >> 3, g = bid & 7;
    int t = threadIdx.x;
    float s = 0.f;
    for (int k = 0; k < 128; ++k)
        s += h[(size_t)(b * LTOT + g * 128 + k) * DM + t];
    part[(size_t)bid * DM + t] = s;
}

// ---------------- head ----------------
__global__ __launch_bounds__(256) void k_head(const float* __restrict__ part,
                                              const float* __restrict__ w1,
                                              const float* __restrict__ b1,
                                              const float* __restrict__ w2,
                                              const float* __restrict__ b2,
                                              float* __restrict__ out) {
    __shared__ float pl[DM], hl[DM];
    int b = blockIdx.x, t = threadIdx.x;
    float s = 0.f;
    for (int g = 0; g < 8; ++g) s += part[(size_t)(b * 8 + g) * DM + t];
    pl[t] = s * (1.f / LTOT);
    __syncthreads();
    float a = b1[t];
    for (int k = 0; k < DM; ++k) a = fmaf(pl[k], w1[(size_t)t * DM + k], a);
    hl[t] = fmaxf(a, 0.f);
    __syncthreads();
    if (t < NH) {
        float o = b2[t];
        for (int k = 0; k < DM; ++k) o = fmaf(hl[k], w2[(size_t)t * DM + k], o);
        out[b * NH + t] = o;
    }
}

extern "C" void kernel_launch(void* const* d_in, const int* in_sizes, int n_in,
                              void* d_out, int out_size, void* d_ws, size_t ws_size,
                              hipStream_t stream) {
    const float* x        = (const float*)d_in[0];
    const float* proj_w   = (const float*)d_in[1];
    const float* proj_b   = (const float*)d_in[2];
    const float* inproj_w = (const float*)d_in[3];
    const float* conv_w   = (const float*)d_in[4];
    const float* conv_b   = (const float*)d_in[5];
    const float* xproj_w  = (const float*)d_in[6];
    const float* dtproj_w = (const float*)d_in[7];
    const float* dtproj_b = (const float*)d_in[8];
    const float* A_log    = (const float*)d_in[9];
    const float* Dp       = (const float*)d_in[10];
    const float* outproj_w= (const float*)d_in[11];
    const float* ln_g     = (const float*)d_in[12];
    const float* ln_b     = (const float*)d_in[13];
    const float* head_w1  = (const float*)d_in[14];
    const float* head_b1  = (const float*)d_in[15];
    const float* head_w2  = (const float*)d_in[16];
    const float* head_b2  = (const float*)d_in[17];

    float* ws    = (float*)d_ws;
    float* h     = ws;                    // 4096*256
    float* xz    = h + 1048576;           // 4096*1024
    float* uc    = xz + 4194304;          // 4096*512 (after scanC: gemm_out partials 2,3)
    float* delta = uc + 2097152;          // 4096*512 (after scanC: gemm_out partials 0,1)
    float* BC    = delta + 2097152;       // 4096*32
    float* Pbuf  = BC + 131072;           // 4*16*8192
    float* hLbuf = Pbuf + 524288;         // 4*16*8192
    float* part  = hLbuf + 524288;        // 32*256
    unsigned short* h_hi  = (unsigned short*)(part + 8192);  // 4096*256 ush
    unsigned short* h_lo  = h_hi + 1048576;
    unsigned short* y_hi  = h_lo + 1048576;                  // 4096*512 ush
    unsigned short* y_lo  = y_hi + 2097152;
    unsigned short* iw_hi = y_lo + 2097152;                  // 4*1024*256 ush
    unsigned short* iw_lo = iw_hi + 1048576;
    unsigned short* ow_hi = iw_lo + 1048576;                 // 4*256*512 ush
    unsigned short* ow_lo = ow_hi + 524288;

    k_splitw<<<1536, 256, 0, stream>>>(inproj_w, outproj_w, iw_hi, iw_lo, ow_hi, ow_lo);
    k_proj<<<ROWS / 16, 256, 0, stream>>>(x, proj_w, proj_b, h, h_hi, h_lo);

    for (int i = 0; i < NLAY; ++i) {
        const float* cwi  = conv_w + (size_t)i * DI * 4;
        const float* cbi  = conv_b + (size_t)i * DI;
        const float* xpw  = xproj_w + (size_t)i * NXP * DI;
        const float* dtw  = dtproj_w + (size_t)i * DI * DTRN;
        const float* dtb  = dtproj_b + (size_t)i * DI;
        const float* Ali  = A_log + (size_t)i * DI * DS;
        const float* Dpi  = Dp + (size_t)i * DI;
        const float* gi   = ln_g + (size_t)i * DM;
        const float* bi   = ln_b + (size_t)i * DM;

        k_gemm_xz<<<512, 256, 0, stream>>>(h_hi, h_lo,
                                           iw_hi + (size_t)i * 262144, iw_lo + (size_t)i * 262144, xz);
        k_conv<<<ROWS * (DI / 4) / 256, 256, 0, stream>>>(xz, cwi, cbi, uc);
        k_dbcp<<<512, 256, 0, stream>>>(uc, xpw, xz);
        k_dbcr<<<ROWS / 16, 256, 0, stream>>>(xz, dtw, dtb, delta, BC);
        k_scanA<<<BB * 32 * NC, 256, 0, stream>>>(delta, uc, BC, Ali, Pbuf, hLbuf);
        k_scanC<<<BB * 32 * NC, 256, 0, stream>>>(delta, uc, BC, Ali, Pbuf, hLbuf, Dpi, xz, y_hi, y_lo);
        // gemm_out partials overwrite delta (kp 0,1) and uc (kp 2,3) — both dead after scanC
        k_gemm_out<<<512, 256, 0, stream>>>(y_hi, y_lo,
                                            ow_hi + (size_t)i * 131072, ow_lo + (size_t)i * 131072,
                                            delta, uc);
        k_ln_res<<<ROWS, 256, 0, stream>>>(delta, uc, gi, bi, h, h_hi, h_lo);
    }

    k_meanp<<<32, 256, 0, stream>>>(h, part);
    k_head<<<BB, 256, 0, stream>>>(part, head_w1, head_b1, head_w2, head_b2, (float*)d_out);
}

// Round 2
// 482.684 us; speedup vs baseline: 1.1052x; 1.0503x over previous
//
#include <hip/hip_runtime.h>
#include <hip/hip_fp16.h>
#include <math.h>

// Problem dims
#define LTOT 1024
#define BB   4
#define F_IN 32
#define DM   256
#define DI   512
#define DS   16
#define DTRN 16
#define NXP  48         // DTR + 2*DS
#define NLAY 4
#define NH   4
#define NC   16         // scan chunks
#define CLEN 64         // L / NC
#define ROWS (BB*LTOT)  // 4096

typedef _Float16 half8 __attribute__((ext_vector_type(8)));
typedef float f32x16 __attribute__((ext_vector_type(16)));
typedef unsigned short us8 __attribute__((ext_vector_type(8)));

__device__ __forceinline__ float siluf_(float x) { return x / (1.0f + expf(-x)); }
__device__ __forceinline__ float softplusf_(float x) {
    if (x > 20.f) return x;
    if (x < -20.f) return expf(x);
    return log1pf(expf(x));
}

// fp16 2-piece split: x ~= hi + lo with ~22-bit combined mantissa
__device__ __forceinline__ void split16(float x, unsigned short& hi, unsigned short& lo) {
    __half h = __float2half(x);
    hi = *(unsigned short*)&h;
    float r = x - __half2float(h);
    __half l = __float2half(r);
    lo = *(unsigned short*)&l;
}

// ---------------- init: fused weight-split (blocks 0..1535) + proj (blocks 1536..1791) ----
__global__ __launch_bounds__(256) void k_init(const float* __restrict__ x,
                                              const float* __restrict__ pw,
                                              const float* __restrict__ pb,
                                              const float* __restrict__ inw,
                                              const float* __restrict__ outw,
                                              float* __restrict__ h,
                                              unsigned short* __restrict__ hh,
                                              unsigned short* __restrict__ hl,
                                              unsigned short* __restrict__ iwh,
                                              unsigned short* __restrict__ iwl,
                                              unsigned short* __restrict__ owh,
                                              unsigned short* __restrict__ owl) {
    __shared__ float wl[DM][33];
    __shared__ float xl[16][32];
    int bid = blockIdx.x, t = threadIdx.x;
    if (bid < 1536) {   // ---- weight split ----
        int q = bid * 256 + t;
        ushort4 h4, l4;
        if (q < 262144) {                          // 4*1024*256 / 4
            float4 v = ((const float4*)inw)[q];
            split16(v.x, h4.x, l4.x); split16(v.y, h4.y, l4.y);
            split16(v.z, h4.z, l4.z); split16(v.w, h4.w, l4.w);
            *(ushort4*)(iwh + (size_t)q * 4) = h4;
            *(ushort4*)(iwl + (size_t)q * 4) = l4;
        } else {
            int r = q - 262144;                    // 4*256*512 / 4 = 131072 quads
            float4 v = ((const float4*)outw)[r];
            split16(v.x, h4.x, l4.x); split16(v.y, h4.y, l4.y);
            split16(v.z, h4.z, l4.z); split16(v.w, h4.w, l4.w);
            *(ushort4*)(owh + (size_t)r * 4) = h4;
            *(ushort4*)(owl + (size_t)r * 4) = l4;
        }
        return;
    }
    // ---- proj: h = x @ proj_w.T + proj_b (+ fp16-split emit) ----
    int r0 = (bid - 1536) * 16;
    for (int i = t; i < DM * 32 / 4; i += 256) {
        float4 v = ((const float4*)pw)[i];
        int c = i / 8, k = (i % 8) * 4;
        wl[c][k] = v.x; wl[c][k + 1] = v.y; wl[c][k + 2] = v.z; wl[c][k + 3] = v.w;
    }
    for (int i = t; i < 16 * 32 / 4; i += 256) {
        float4 v = ((const float4*)(x + (size_t)r0 * F_IN))[i];
        int r = i / 8, k = (i % 8) * 4;
        xl[r][k] = v.x; xl[r][k + 1] = v.y; xl[r][k + 2] = v.z; xl[r][k + 3] = v.w;
    }
    __syncthreads();
    int c = t;
    float bias = pb[c];
    float acc[16];
#pragma unroll
    for (int r = 0; r < 16; ++r) acc[r] = bias;
    for (int k = 0; k < 32; ++k) {
        float w = wl[c][k];
#pragma unroll
        for (int r = 0; r < 16; ++r) acc[r] = fmaf(xl[r][k], w, acc[r]);
    }
#pragma unroll
    for (int r = 0; r < 16; ++r) {
        size_t idx = (size_t)(r0 + r) * DM + c;
        h[idx] = acc[r];
        unsigned short vh, vl; split16(acc[r], vh, vl);
        hh[idx] = vh; hl[idx] = vl;
    }
}

// ---------------- gemm_xz (MFMA, pre-split fp16): xz = h @ inw^T ----------------
// 64x128 tile, grid 512 = 64 rowblk x 8 colblk (2 blocks/CU).
__global__ __launch_bounds__(256) void k_gemm_xz(const unsigned short* __restrict__ Ahp,
                                                 const unsigned short* __restrict__ Alp,
                                                 const unsigned short* __restrict__ Bhp,
                                                 const unsigned short* __restrict__ Blp,
                                                 float* __restrict__ C) {
    __shared__ unsigned short Ah[64][40], Al[64][40], Bh[128][40], Bl[128][40];
    int t = threadIdx.x;
    int bx = blockIdx.x & 7;
    int by = blockIdx.x >> 3;
    int rowA = t >> 2, kA = (t & 3) * 8;   // 64 rows x 4 granules of 8 ushorts
    int rowB = t >> 1, kB = (t & 1) * 16;  // 128 rows x 2 granules of 16 ushorts
    const unsigned short* ApH = Ahp + (size_t)(by * 64 + rowA) * DM + kA;
    const unsigned short* ApL = Alp + (size_t)(by * 64 + rowA) * DM + kA;
    const unsigned short* BpH = Bhp + (size_t)(bx * 128 + rowB) * DM + kB;
    const unsigned short* BpL = Blp + (size_t)(bx * 128 + rowB) * DM + kB;
    us8 rah = *(const us8*)ApH, ral = *(const us8*)ApL;
    us8 rbh0 = *(const us8*)BpH, rbh1 = *(const us8*)(BpH + 8);
    us8 rbl0 = *(const us8*)BpL, rbl1 = *(const us8*)(BpL + 8);
    int lane = t & 63, wid = t >> 6;
    int fr = lane & 31, fg = lane >> 5;
    int wr = wid >> 1, wc = wid & 1;
    f32x16 acc[2] = {};
    for (int k0 = 0; k0 < DM; k0 += 32) {
        *(us8*)&Ah[rowA][kA] = rah;
        *(us8*)&Al[rowA][kA] = ral;
        *(us8*)&Bh[rowB][kB] = rbh0; *(us8*)&Bh[rowB][kB + 8] = rbh1;
        *(us8*)&Bl[rowB][kB] = rbl0; *(us8*)&Bl[rowB][kB + 8] = rbl1;
        __syncthreads();
        if (k0 + 32 < DM) {
            rah = *(const us8*)(ApH + k0 + 32); ral = *(const us8*)(ApL + k0 + 32);
            rbh0 = *(const us8*)(BpH + k0 + 32); rbh1 = *(const us8*)(BpH + k0 + 40);
            rbl0 = *(const us8*)(BpL + k0 + 32); rbl1 = *(const us8*)(BpL + k0 + 40);
        }
#pragma unroll
        for (int s = 0; s < 2; ++s) {
            int ko = s * 16 + fg * 8;
            half8 ah = *(const half8*)&Ah[wr * 32 + fr][ko];
            half8 al = *(const half8*)&Al[wr * 32 + fr][ko];
#pragma unroll
            for (int fc = 0; fc < 2; ++fc) {
                half8 bh = *(const half8*)&Bh[wc * 64 + fc * 32 + fr][ko];
                half8 bl = *(const half8*)&Bl[wc * 64 + fc * 32 + fr][ko];
                acc[fc] = __builtin_amdgcn_mfma_f32_32x32x16_f16(ah, bh, acc[fc], 0, 0, 0);
                acc[fc] = __builtin_amdgcn_mfma_f32_32x32x16_f16(ah, bl, acc[fc], 0, 0, 0);
                acc[fc] = __builtin_amdgcn_mfma_f32_32x32x16_f16(al, bh, acc[fc], 0, 0, 0);
            }
        }
        __syncthreads();
    }
    float* Cp = C + (size_t)(by * 64 + wr * 32) * 1024 + bx * 128 + wc * 64;
#pragma unroll
    for (int fc = 0; fc < 2; ++fc) {
#pragma unroll
        for (int reg = 0; reg < 16; ++reg) {
            int row = (reg & 3) + 8 * (reg >> 2) + 4 * fg;
            Cp[(size_t)row * 1024 + fc * 32 + fr] = acc[fc][reg];
        }
    }
}

// ---------------- dbc partial GEMM (split-K by 4) with fused causal conv+silu --------
// Computes uc tile from xz in-kernel (writes uc global for scan kernels),
// stages it to LDS, multiplies by xproj slice; partials -> dbp (stride 192).
__global__ __launch_bounds__(256) void k_dbcp(const float* __restrict__ xz,
                                              const float* __restrict__ cw,
                                              const float* __restrict__ cb,
                                              const float* __restrict__ xpw,
                                              float* __restrict__ uc,
                                              float* __restrict__ dbp) {
    __shared__ float us[32][132];
    __shared__ float wsd[48][132];
    int t = threadIdx.x;
    int kp = blockIdx.x & 3;
    int r0 = (blockIdx.x >> 2) * 32;
    int k0 = kp * 128;
    float4* us4 = (float4*)us;
    float4* ws4 = (float4*)wsd;
#pragma unroll
    for (int j = 0; j < 4; ++j) {
        int i = t + j * 256;
        int r = i >> 5, kq = i & 31;
        int rr = r0 + r, d = k0 + kq * 4;
        int tt = rr & (LTOT - 1);
        float4 acc = make_float4(cb[d], cb[d + 1], cb[d + 2], cb[d + 3]);
#pragma unroll
        for (int k = 0; k < 4; ++k) {
            int ts = tt - 3 + k;
            if (ts < 0) continue;
            float4 u = *(const float4*)(xz + (size_t)(rr - 3 + k) * 1024 + d);
            acc.x = fmaf(u.x, cw[(d + 0) * 4 + k], acc.x);
            acc.y = fmaf(u.y, cw[(d + 1) * 4 + k], acc.y);
            acc.z = fmaf(u.z, cw[(d + 2) * 4 + k], acc.z);
            acc.w = fmaf(u.w, cw[(d + 3) * 4 + k], acc.w);
        }
        acc.x = siluf_(acc.x); acc.y = siluf_(acc.y); acc.z = siluf_(acc.z); acc.w = siluf_(acc.w);
        us4[r * 33 + kq] = acc;
        *(float4*)(uc + (size_t)rr * DI + d) = acc;
    }
#pragma unroll
    for (int j = 0; j < 6; ++j) {
        int i = t + j * 256;
        int r = i >> 5, kq = i & 31;
        ws4[r * 33 + kq] = *(const float4*)(xpw + (size_t)r * DI + k0 + kq * 4);
    }
    __syncthreads();
    int tx = t & 15, ty = t >> 4;
    const float4* ua = us4 + (ty * 2) * 33;
    const float4* ub = ua + 33;
    const float4* w0p = ws4 + (tx * 3) * 33;
    const float4* w1p = w0p + 33;
    const float4* w2p = w0p + 66;
    float acc[2][3] = {};
#pragma unroll 4
    for (int kq = 0; kq < 32; ++kq) {
        float4 u0 = ua[kq], u1 = ub[kq];
        float4 w0 = w0p[kq], w1 = w1p[kq], w2 = w2p[kq];
        acc[0][0] = fmaf(u0.x, w0.x, acc[0][0]); acc[0][0] = fmaf(u0.y, w0.y, acc[0][0]);
        acc[0][0] = fmaf(u0.z, w0.z, acc[0][0]); acc[0][0] = fmaf(u0.w, w0.w, acc[0][0]);
        acc[0][1] = fmaf(u0.x, w1.x, acc[0][1]); acc[0][1] = fmaf(u0.y, w1.y, acc[0][1]);
        acc[0][1] = fmaf(u0.z, w1.z, acc[0][1]); acc[0][1] = fmaf(u0.w, w1.w, acc[0][1]);
        acc[0][2] = fmaf(u0.x, w2.x, acc[0][2]); acc[0][2] = fmaf(u0.y, w2.y, acc[0][2]);
        acc[0][2] = fmaf(u0.z, w2.z, acc[0][2]); acc[0][2] = fmaf(u0.w, w2.w, acc[0][2]);
        acc[1][0] = fmaf(u1.x, w0.x, acc[1][0]); acc[1][0] = fmaf(u1.y, w0.y, acc[1][0]);
        acc[1][0] = fmaf(u1.z, w0.z, acc[1][0]); acc[1][0] = fmaf(u1.w, w0.w, acc[1][0]);
        acc[1][1] = fmaf(u1.x, w1.x, acc[1][1]); acc[1][1] = fmaf(u1.y, w1.y, acc[1][1]);
        acc[1][1] = fmaf(u1.z, w1.z, acc[1][1]); acc[1][1] = fmaf(u1.w, w1.w, acc[1][1]);
        acc[1][2] = fmaf(u1.x, w2.x, acc[1][2]); acc[1][2] = fmaf(u1.y, w2.y, acc[1][2]);
        acc[1][2] = fmaf(u1.z, w2.z, acc[1][2]); acc[1][2] = fmaf(u1.w, w2.w, acc[1][2]);
    }
    float* outp = dbp + (size_t)(r0 + ty * 2) * 192 + kp * 48 + tx * 3;
    outp[0] = acc[0][0]; outp[1] = acc[0][1]; outp[2] = acc[0][2];
    outp[192] = acc[1][0]; outp[193] = acc[1][1]; outp[194] = acc[1][2];
}

// ---------------- scan pass A (fused dbc-reduce + delta) ----------------
__global__ __launch_bounds__(256) void k_scanA(const float* __restrict__ dbp,
                                               const float* __restrict__ uc,
                                               const float* __restrict__ dtw,
                                               const float* __restrict__ dtb,
                                               const float* __restrict__ A_log,
                                               float* __restrict__ P,
                                               float* __restrict__ hL) {
    __shared__ float2 du2[CLEN][16];
    __shared__ float  Bl[CLEN][16];
    __shared__ float  dbl[CLEN][17];
    __shared__ float  wdl[16][17];
    __shared__ float  wbias[16];
    int bid = blockIdx.x;
    int c = bid & 15, dblk = (bid >> 4) & 31, b = bid >> 9;
    int d0 = dblk * 16, t0 = c * CLEN;
    int t = threadIdx.x;
    int row = t >> 2, q4 = (t & 3) * 4;
    size_t rbase = (size_t)(b * LTOT + t0 + row);
    float4 uv = *(const float4*)(uc + rbase * DI + d0 + q4);
    {
        const float* pp = dbp + rbase * 192;
        float4 a0 = *(const float4*)(pp + q4);
        float4 a1 = *(const float4*)(pp + 48 + q4);
        float4 a2 = *(const float4*)(pp + 96 + q4);
        float4 a3 = *(const float4*)(pp + 144 + q4);
        dbl[row][q4 + 0] = ((a0.x + a1.x) + a2.x) + a3.x;
        dbl[row][q4 + 1] = ((a0.y + a1.y) + a2.y) + a3.y;
        dbl[row][q4 + 2] = ((a0.z + a1.z) + a2.z) + a3.z;
        dbl[row][q4 + 3] = ((a0.w + a1.w) + a2.w) + a3.w;
        float4 b0 = *(const float4*)(pp + 16 + q4);
        float4 b1 = *(const float4*)(pp + 64 + q4);
        float4 b2 = *(const float4*)(pp + 112 + q4);
        float4 b3 = *(const float4*)(pp + 160 + q4);
        Bl[row][q4 + 0] = ((b0.x + b1.x) + b2.x) + b3.x;
        Bl[row][q4 + 1] = ((b0.y + b1.y) + b2.y) + b3.y;
        Bl[row][q4 + 2] = ((b0.z + b1.z) + b2.z) + b3.z;
        Bl[row][q4 + 3] = ((b0.w + b1.w) + b2.w) + b3.w;
    }
    if (t < 64) {
        int dd = t >> 2, sg = (t & 3) * 4;
        const float* wp = dtw + (size_t)(d0 + dd) * 16 + sg;
        wdl[dd][sg + 0] = wp[0]; wdl[dd][sg + 1] = wp[1];
        wdl[dd][sg + 2] = wp[2]; wdl[dd][sg + 3] = wp[3];
    }
    if (t < 16) wbias[t] = dtb[d0 + t];
    __syncthreads();
    {
        float s0 = wbias[q4 + 0], s1 = wbias[q4 + 1], s2 = wbias[q4 + 2], s3 = wbias[q4 + 3];
#pragma unroll
        for (int k = 0; k < 16; ++k) {
            float dv = dbl[row][k];
            s0 = fmaf(dv, wdl[q4 + 0][k], s0);
            s1 = fmaf(dv, wdl[q4 + 1][k], s1);
            s2 = fmaf(dv, wdl[q4 + 2][k], s2);
            s3 = fmaf(dv, wdl[q4 + 3][k], s3);
        }
        du2[row][q4 + 0] = make_float2(softplusf_(s0), uv.x);
        du2[row][q4 + 1] = make_float2(softplusf_(s1), uv.y);
        du2[row][q4 + 2] = make_float2(softplusf_(s2), uv.z);
        du2[row][q4 + 3] = make_float2(softplusf_(s3), uv.w);
    }
    __syncthreads();
    int n = t & 15, dn = t >> 4;
    float Ac = -expf(A_log[(size_t)(d0 + dn) * DS + n]);
    float h = 0.f, Pp = 1.f;
#pragma unroll 8
    for (int k = 0; k < CLEN; ++k) {
        float2 du = du2[k][dn];
        float Bv = Bl[k][n];
        float a = expf(du.x * Ac);
        Pp *= a;
        h = fmaf(a, h, du.x * du.y * Bv);
    }
    size_t idx = ((size_t)(b * NC + c)) * (DI * DS) + (size_t)d0 * DS + t;
    P[idx] = Pp;
    hL[idx] = h;
}

// ---------------- scan pass C (fused dbc-reduce + delta; emits fp16-split y) ---------
__global__ __launch_bounds__(256) void k_scanC(const float* __restrict__ dbp,
                                               const float* __restrict__ uc,
                                               const float* __restrict__ dtw,
                                               const float* __restrict__ dtb,
                                               const float* __restrict__ A_log,
                                               const float* __restrict__ P,
                                               const float* __restrict__ hL,
                                               const float* __restrict__ Dp,
                                               const float* __restrict__ xz,
                                               unsigned short* __restrict__ yh,
                                               unsigned short* __restrict__ yl) {
    __shared__ float2 du2[CLEN][16];
    __shared__ float2 bc2[CLEN][16];
    __shared__ float  ytmp[16][16][20];   // 5120 floats; prologue aliases scratch inside
    float* scr = &ytmp[0][0][0];
    float (*dbl)[17] = (float(*)[17])scr;           // 64*17 = 1088
    float (*wdl)[17] = (float(*)[17])(scr + 1088);  // 16*17 = 272
    float* wbias = scr + 1088 + 272;                // 16
    int bid = blockIdx.x;
    int c = bid & 15, dblk = (bid >> 4) & 31, b = bid >> 9;
    int d0 = dblk * 16, t0 = c * CLEN;
    int t = threadIdx.x;
    int row = t >> 2, q4 = (t & 3) * 4;
    size_t rbase = (size_t)(b * LTOT + t0 + row);
    float4 uv = *(const float4*)(uc + rbase * DI + d0 + q4);
    {
        const float* pp = dbp + rbase * 192;
        float4 a0 = *(const float4*)(pp + q4);
        float4 a1 = *(const float4*)(pp + 48 + q4);
        float4 a2 = *(const float4*)(pp + 96 + q4);
        float4 a3 = *(const float4*)(pp + 144 + q4);
        dbl[row][q4 + 0] = ((a0.x + a1.x) + a2.x) + a3.x;
        dbl[row][q4 + 1] = ((a0.y + a1.y) + a2.y) + a3.y;
        dbl[row][q4 + 2] = ((a0.z + a1.z) + a2.z) + a3.z;
        dbl[row][q4 + 3] = ((a0.w + a1.w) + a2.w) + a3.w;
        float4 b0 = *(const float4*)(pp + 16 + q4);
        float4 b1 = *(const float4*)(pp + 64 + q4);
        float4 b2 = *(const float4*)(pp + 112 + q4);
        float4 b3 = *(const float4*)(pp + 160 + q4);
        float4 c0 = *(const float4*)(pp + 32 + q4);
        float4 c1 = *(const float4*)(pp + 80 + q4);
        float4 c2 = *(const float4*)(pp + 128 + q4);
        float4 c3 = *(const float4*)(pp + 176 + q4);
        float B0 = ((b0.x + b1.x) + b2.x) + b3.x, C0 = ((c0.x + c1.x) + c2.x) + c3.x;
        float B1 = ((b0.y + b1.y) + b2.y) + b3.y, C1 = ((c0.y + c1.y) + c2.y) + c3.y;
        float B2 = ((b0.z + b1.z) + b2.z) + b3.z, C2 = ((c0.z + c1.z) + c2.z) + c3.z;
        float B3 = ((b0.w + b1.w) + b2.w) + b3.w, C3 = ((c0.w + c1.w) + c2.w) + c3.w;
        bc2[row][q4 + 0] = make_float2(B0, C0);
        bc2[row][q4 + 1] = make_float2(B1, C1);
        bc2[row][q4 + 2] = make_float2(B2, C2);
        bc2[row][q4 + 3] = make_float2(B3, C3);
    }
    if (t < 64) {
        int dd = t >> 2, sg = (t & 3) * 4;
        const float* wp = dtw + (size_t)(d0 + dd) * 16 + sg;
        wdl[dd][sg + 0] = wp[0]; wdl[dd][sg + 1] = wp[1];
        wdl[dd][sg + 2] = wp[2]; wdl[dd][sg + 3] = wp[3];
    }
    if (t < 16) wbias[t] = dtb[d0 + t];
    __syncthreads();
    {
        float s0 = wbias[q4 + 0], s1 = wbias[q4 + 1], s2 = wbias[q4 + 2], s3 = wbias[q4 + 3];
#pragma unroll
        for (int k = 0; k < 16; ++k) {
            float dv = dbl[row][k];
            s0 = fmaf(dv, wdl[q4 + 0][k], s0);
            s1 = fmaf(dv, wdl[q4 + 1][k], s1);
            s2 = fmaf(dv, wdl[q4 + 2][k], s2);
            s3 = fmaf(dv, wdl[q4 + 3][k], s3);
        }
        du2[row][q4 + 0] = make_float2(softplusf_(s0), uv.x);
        du2[row][q4 + 1] = make_float2(softplusf_(s1), uv.y);
        du2[row][q4 + 2] = make_float2(softplusf_(s2), uv.z);
        du2[row][q4 + 3] = make_float2(softplusf_(s3), uv.w);
    }
    __syncthreads();   // dbl/wdl (aliased into ytmp) dead from here; du2/bc2 visible
    int n = t & 15, dn = t >> 4;
    float Ac = -expf(A_log[(size_t)(d0 + dn) * DS + n]);
    float Hin = 0.f;
    for (int cc = 0; cc < c; ++cc) {
        size_t idx = ((size_t)(b * NC + cc)) * (DI * DS) + (size_t)d0 * DS + t;
        Hin = fmaf(P[idx], Hin, hL[idx]);
    }
    float h = Hin;
    int rdn = t & 15, rk = t >> 4;
    float DpV = Dp[d0 + rdn];
    for (int s = 0; s < CLEN / 16; ++s) {
#pragma unroll
        for (int kk = 0; kk < 16; ++kk) {
            int k = s * 16 + kk;
            float2 du = du2[k][dn];
            float2 bc = bc2[k][n];
            float a = expf(du.x * Ac);
            h = fmaf(a, h, du.x * du.y * bc.x);
            ytmp[kk][dn][n] = h * bc.y;
        }
        __syncthreads();
        {
            const float* rowp = &ytmp[rk][rdn][0];
            float4 v0 = *(const float4*)(rowp + 0);
            float4 v1 = *(const float4*)(rowp + 4);
            float4 v2 = *(const float4*)(rowp + 8);
            float4 v3 = *(const float4*)(rowp + 12);
            float y = ((v0.x + v0.y) + (v0.z + v0.w)) + ((v1.x + v1.y) + (v1.z + v1.w))
                    + ((v2.x + v2.y) + (v2.z + v2.w)) + ((v3.x + v3.y) + (v3.z + v3.w));
            float uu = du2[s * 16 + rk][rdn].y;
            size_t rb2 = (size_t)(b * LTOT + t0 + s * 16 + rk);
            float z = xz[rb2 * 1024 + 512 + d0 + rdn];
            float val = fmaf(uu, DpV, y) * siluf_(z);
            unsigned short vh, vl; split16(val, vh, vl);
            size_t yi = rb2 * DI + d0 + rdn;
            yh[yi] = vh; yl[yi] = vl;
        }
        __syncthreads();
    }
}

// ---------------- gemm_out (MFMA, pre-split fp16, split-K4): blk = yz @ outw^T ----
__global__ __launch_bounds__(256) void k_gemm_out(const unsigned short* __restrict__ Ahp,
                                                  const unsigned short* __restrict__ Alp,
                                                  const unsigned short* __restrict__ Bhp,
                                                  const unsigned short* __restrict__ Blp,
                                                  float* __restrict__ p01,
                                                  float* __restrict__ p23) {
    __shared__ unsigned short Ah[64][40], Al[64][40], Bh[128][40], Bl[128][40];
    int t = threadIdx.x;
    int bx = blockIdx.x & 1;
    int by = (blockIdx.x >> 1) & 63;
    int kp = blockIdx.x >> 7;
    int rowA = t >> 2, kA = (t & 3) * 8;
    int rowB = t >> 1, kB = (t & 1) * 16;
    const unsigned short* ApH = Ahp + (size_t)(by * 64 + rowA) * DI + kp * 128 + kA;
    const unsigned short* ApL = Alp + (size_t)(by * 64 + rowA) * DI + kp * 128 + kA;
    const unsigned short* BpH = Bhp + (size_t)(bx * 128 + rowB) * DI + kp * 128 + kB;
    const unsigned short* BpL = Blp + (size_t)(bx * 128 + rowB) * DI + kp * 128 + kB;
    us8 rah = *(const us8*)ApH, ral = *(const us8*)ApL;
    us8 rbh0 = *(const us8*)BpH, rbh1 = *(const us8*)(BpH + 8);
    us8 rbl0 = *(const us8*)BpL, rbl1 = *(const us8*)(BpL + 8);
    int lane = t & 63, wid = t >> 6;
    int fr = lane & 31, fg = lane >> 5;
    int wr = wid >> 1, wc = wid & 1;
    f32x16 acc[2] = {};
    for (int k0 = 0; k0 < 128; k0 += 32) {
        *(us8*)&Ah[rowA][kA] = rah;
        *(us8*)&Al[rowA][kA] = ral;
        *(us8*)&Bh[rowB][kB] = rbh0; *(us8*)&Bh[rowB][kB + 8] = rbh1;
        *(us8*)&Bl[rowB][kB] = rbl0; *(us8*)&Bl[rowB][kB + 8] = rbl1;
        __syncthreads();
        if (k0 + 32 < 128) {
            rah = *(const us8*)(ApH + k0 + 32); ral = *(const us8*)(ApL + k0 + 32);
            rbh0 = *(const us8*)(BpH + k0 + 32); rbh1 = *(const us8*)(BpH + k0 + 40);
            rbl0 = *(const us8*)(BpL + k0 + 32); rbl1 = *(const us8*)(BpL + k0 + 40);
        }
#pragma unroll
        for (int s = 0; s < 2; ++s) {
            int ko = s * 16 + fg * 8;
            half8 ah = *(const half8*)&Ah[wr * 32 + fr][ko];
            half8 al = *(const half8*)&Al[wr * 32 + fr][ko];
#pragma unroll
            for (int fc = 0; fc < 2; ++fc) {
                half8 bh = *(const half8*)&Bh[wc * 64 + fc * 32 + fr][ko];
                half8 bl = *(const half8*)&Bl[wc * 64 + fc * 32 + fr][ko];
                acc[fc] = __builtin_amdgcn_mfma_f32_32x32x16_f16(ah, bh, acc[fc], 0, 0, 0);
                acc[fc] = __builtin_amdgcn_mfma_f32_32x32x16_f16(ah, bl, acc[fc], 0, 0, 0);
                acc[fc] = __builtin_amdgcn_mfma_f32_32x32x16_f16(al, bh, acc[fc], 0, 0, 0);
            }
        }
        __syncthreads();
    }
    float* pbase = (kp < 2 ? p01 : p23) + (size_t)(kp & 1) * (ROWS * DM);
    float* Cp = pbase + (size_t)(by * 64 + wr * 32) * DM + bx * 128 + wc * 64;
#pragma unroll
    for (int fc = 0; fc < 2; ++fc) {
#pragma unroll
        for (int reg = 0; reg < 16; ++reg) {
            int row = (reg & 3) + 8 * (reg >> 2) + 4 * fg;
            Cp[(size_t)row * DM + fc * 32 + fr] = acc[fc][reg];
        }
    }
}

// ---------------- layernorm + residual (sums 4 gemm_out partials, emits h16) --------
__global__ __launch_bounds__(256) void k_ln_res(const float* __restrict__ p01,
                                                const float* __restrict__ p23,
                                                const float* __restrict__ g,
                                                const float* __restrict__ bb,
                                                float* __restrict__ h,
                                                unsigned short* __restrict__ hh,
                                                unsigned short* __restrict__ hl) {
    __shared__ float scratch[4];
    int r = blockIdx.x, t = threadIdx.x;
    size_t idx = (size_t)r * DM + t;
    float v = p01[idx] + p01[idx + (size_t)ROWS * DM] + p23[idx] + p23[idx + (size_t)ROWS * DM];
    float s = v;
#pragma unroll
    for (int m = 32; m >= 1; m >>= 1) s += __shfl_xor(s, m, 64);
    if ((t & 63) == 0) scratch[t >> 6] = s;
    __syncthreads();
    float mu = (scratch[0] + scratch[1] + scratch[2] + scratch[3]) * (1.f / DM);
    __syncthreads();
    float d = v - mu;
    float s2 = d * d;
#pragma unroll
    for (int m = 32; m >= 1; m >>= 1) s2 += __shfl_xor(s2, m, 64);
    if ((t & 63) == 0) scratch[t >> 6] = s2;
    __syncthreads();
    float var = (scratch[0] + scratch[1] + scratch[2] + scratch[3]) * (1.f / DM);
    float rstd = 1.f / sqrtf(var + 1e-5f);
    float nv = h[idx] + d * rstd * g[t] + bb[t];
    h[idx] = nv;
    unsigned short vh, vl; split16(nv, vh, vl);
    hh[idx] = vh; hl[idx] = vl;
}

// ---------------- mean over L (partials, deterministic) ----------------
__global__ __launch_bounds__(256) void k_meanp(const float* __restrict__ h,
                                               float* __restrict__ part) {
    int bid = blockIdx.x;
    int b = bid >> 3, g = bid & 7;
    int t = threadIdx.x;
    float s = 0.f;
    for (int k = 0; k < 128; ++k)
        s += h[(size_t)(b * LTOT + g * 128 + k) * DM + t];
    part[(size_t)bid * DM + t] = s;
}

// ---------------- head ----------------
__global__ __launch_bounds__(256) void k_head(const float* __restrict__ part,
                                              const float* __restrict__ w1,
                                              const float* __restrict__ b1,
                                              const float* __restrict__ w2,
                                              const float* __restrict__ b2,
                                              float* __restrict__ out) {
    __shared__ float pl[DM], hl[DM];
    int b = blockIdx.x, t = threadIdx.x;
    float s = 0.f;
    for (int g = 0; g < 8; ++g) s += part[(size_t)(b * 8 + g) * DM + t];
    pl[t] = s * (1.f / LTOT);
    __syncthreads();
    float a = b1[t];
    for (int k = 0; k < DM; ++k) a = fmaf(pl[k], w1[(size_t)t * DM + k], a);
    hl[t] = fmaxf(a, 0.f);
    __syncthreads();
    if (t < NH) {
        float o = b2[t];
        for (int k = 0; k < DM; ++k) o = fmaf(hl[k], w2[(size_t)t * DM + k], o);
        out[b * NH + t] = o;
    }
}

extern "C" void kernel_launch(void* const* d_in, const int* in_sizes, int n_in,
                              void* d_out, int out_size, void* d_ws, size_t ws_size,
                              hipStream_t stream) {
    const float* x        = (const float*)d_in[0];
    const float* proj_w   = (const float*)d_in[1];
    const float* proj_b   = (const float*)d_in[2];
    const float* inproj_w = (const float*)d_in[3];
    const float* conv_w   = (const float*)d_in[4];
    const float* conv_b   = (const float*)d_in[5];
    const float* xproj_w  = (const float*)d_in[6];
    const float* dtproj_w = (const float*)d_in[7];
    const float* dtproj_b = (const float*)d_in[8];
    const float* A_log    = (const float*)d_in[9];
    const float* Dp       = (const float*)d_in[10];
    const float* outproj_w= (const float*)d_in[11];
    const float* ln_g     = (const float*)d_in[12];
    const float* ln_b     = (const float*)d_in[13];
    const float* head_w1  = (const float*)d_in[14];
    const float* head_b1  = (const float*)d_in[15];
    const float* head_w2  = (const float*)d_in[16];
    const float* head_b2  = (const float*)d_in[17];

    float* ws    = (float*)d_ws;
    float* h     = ws;                    // 1,048,576 f
    float* xz    = h + 1048576;           // 4,194,304 f
    float* uc    = xz + 4194304;          // 2,097,152 f
    float* dbp   = uc + 2097152;          //   786,432 f (4096*192 dbc partials)
    float* Pbuf  = dbp + 786432;          //   524,288 f
    float* hLbuf = Pbuf + 524288;         //   524,288 f
    float* p01   = hLbuf + 524288;        // 2,097,152 f (gemm_out partials 0,1)
    float* p23   = p01 + 2097152;         // 2,097,152 f (gemm_out partials 2,3)
    float* part  = p23 + 2097152;         //     8,192 f
    unsigned short* h_hi  = (unsigned short*)(part + 8192);  // 4096*256 ush
    unsigned short* h_lo  = h_hi + 1048576;
    unsigned short* y_hi  = h_lo + 1048576;                  // 4096*512 ush
    unsigned short* y_lo  = y_hi + 2097152;
    unsigned short* iw_hi = y_lo + 2097152;                  // 4*1024*256 ush
    unsigned short* iw_lo = iw_hi + 1048576;
    unsigned short* ow_hi = iw_lo + 1048576;                 // 4*256*512 ush
    unsigned short* ow_lo = ow_hi + 524288;

    k_init<<<1792, 256, 0, stream>>>(x, proj_w, proj_b, inproj_w, outproj_w,
                                     h, h_hi, h_lo, iw_hi, iw_lo, ow_hi, ow_lo);

    for (int i = 0; i < NLAY; ++i) {
        const float* cwi  = conv_w + (size_t)i * DI * 4;
        const float* cbi  = conv_b + (size_t)i * DI;
        const float* xpw  = xproj_w + (size_t)i * NXP * DI;
        const float* dtw  = dtproj_w + (size_t)i * DI * DTRN;
        const float* dtb  = dtproj_b + (size_t)i * DI;
        const float* Ali  = A_log + (size_t)i * DI * DS;
        const float* Dpi  = Dp + (size_t)i * DI;
        const float* gi   = ln_g + (size_t)i * DM;
        const float* bi   = ln_b + (size_t)i * DM;

        k_gemm_xz<<<512, 256, 0, stream>>>(h_hi, h_lo,
                                           iw_hi + (size_t)i * 262144, iw_lo + (size_t)i * 262144, xz);
        k_dbcp<<<512, 256, 0, stream>>>(xz, cwi, cbi, xpw, uc, dbp);
        k_scanA<<<BB * 32 * NC, 256, 0, stream>>>(dbp, uc, dtw, dtb, Ali, Pbuf, hLbuf);
        k_scanC<<<BB * 32 * NC, 256, 0, stream>>>(dbp, uc, dtw, dtb, Ali, Pbuf, hLbuf, Dpi, xz, y_hi, y_lo);
        k_gemm_out<<<512, 256, 0, stream>>>(y_hi, y_lo,
                                            ow_hi + (size_t)i * 131072, ow_lo + (size_t)i * 131072,
                                            p01, p23);
        k_ln_res<<<ROWS, 256, 0, stream>>>(p01, p23, gi, bi, h, h_hi, h_lo);
    }

    k_meanp<<<32, 256, 0, stream>>>(h, part);
    k_head<<<BB, 256, 0, stream>>>(part, head_w1, head_b1, head_w2, head_b2, (float*)d_out);
}